// Round 1
// baseline (1303.273 us; speedup 1.0000x reference)
//
#include <hip/hip_runtime.h>
#include <hip/hip_bf16.h>

#define HH 512
#define IN_F 256
#define OUT_F 128
#define NSTEPS 3
#define NL 3
#define RROWS 64
#define STRIDE 520   // bf16 elements; 1040B row pitch -> conflict-free-ish ds_read_b128

typedef __attribute__((ext_vector_type(8))) short short8;
typedef __attribute__((ext_vector_type(4))) float f32x4;
typedef unsigned short u16;
typedef unsigned int u32;

union U16x8 { uint4 u; short8 s; u16 h[8]; };
union U16x4 { uint2 u; u16 h[4]; };

static __device__ __forceinline__ float bf2f(u16 v){
  return __uint_as_float(((u32)v) << 16);
}
static __device__ __forceinline__ u16 f2bf(float f){   // RNE bf16
  u32 x = __float_as_uint(f);
  x += 0x7fffu + ((x >> 16) & 1u);
  return (u16)(x >> 16);
}

// ---------------- prep kernels ----------------

// bf16 conversions; W_liq gets +I folded (pre = h + h@W^T + b == h@(W+I)^T + b)
__global__ void prep_convert(const float* __restrict__ Wliq, const float* __restrict__ Win,
                             const float* __restrict__ W1, const float* __restrict__ W2,
                             u16* __restrict__ oliq, u16* __restrict__ owin,
                             u16* __restrict__ ow1, u16* __restrict__ ow2)
{
  int tid = blockIdx.x * blockDim.x + threadIdx.x;
  int nt  = gridDim.x * blockDim.x;
  for (int i = tid; i < NL*HH*HH; i += nt){
    int rem = i % (HH*HH);
    int r = rem / HH, c = rem % HH;
    oliq[i] = f2bf(Wliq[i] + ((r == c) ? 1.0f : 0.0f));
  }
  for (int i = tid; i < HH*IN_F;  i += nt) owin[i] = f2bf(Win[i]);
  for (int i = tid; i < HH*2*HH;  i += nt) ow1[i]  = f2bf(W1[i]);
  for (int i = tid; i < OUT_F*HH; i += nt) ow2[i]  = f2bf(W2[i]);
}

// W_ov = W_o @ W_v  (so att = liq @ W_ov^T + b_ov), b_ov = W_o @ b_v + b_o
__global__ void prep_ov(const float* __restrict__ Wv, const float* __restrict__ Wo,
                        const float* __restrict__ bv, const float* __restrict__ bo,
                        u16* __restrict__ oov, float* __restrict__ obov)
{
  __shared__ float srow[HH];
  __shared__ float rbuf[256];
  const int i = blockIdx.x;     // output row
  const int t = threadIdx.x;
  srow[t]       = Wo[i*HH + t];
  srow[t + 256] = Wo[i*HH + t + 256];
  __syncthreads();
  #pragma unroll
  for (int half = 0; half < 2; ++half){
    int j = t + half*256;
    float a0 = 0.f, a1 = 0.f;
    for (int k = 0; k < HH; k += 2){
      a0 += srow[k]   * Wv[(k)*HH + j];
      a1 += srow[k+1] * Wv[(k+1)*HH + j];
    }
    oov[i*HH + j] = f2bf(a0 + a1);
  }
  float p = 0.f;
  for (int k = t; k < HH; k += 256) p += srow[k] * bv[k];
  rbuf[t] = p; __syncthreads();
  for (int s = 128; s > 0; s >>= 1){ if (t < s) rbuf[t] += rbuf[t + s]; __syncthreads(); }
  if (t == 0) obov[i] = rbuf[0] + bo[i];
}

// ---------------- main fused kernel ----------------

// wave tile: 32 rows x 128 cols; block tile: 64 rows x 512 cols; 8 waves (2x4)
__device__ __forceinline__ void gemm_tile(const u16* __restrict__ ldsA,
    const u16* __restrict__ W, int Wk, int kSteps,
    int wm, int wn, int lr, int lg, f32x4 (&acc)[2][8])
{
  const int base_a = (wm*32 + lr)*STRIDE + lg*8;
  const int base_w = (wn*128 + lr)*Wk + lg*8;
  #pragma unroll 2
  for (int ks = 0; ks < kSteps; ++ks){
    U16x8 a0, a1;
    a0.u = *reinterpret_cast<const uint4*>(ldsA + base_a + ks*32);
    a1.u = *reinterpret_cast<const uint4*>(ldsA + base_a + 16*STRIDE + ks*32);
    #pragma unroll
    for (int th = 0; th < 2; ++th){
      U16x8 b[4];
      #pragma unroll
      for (int q = 0; q < 4; ++q){
        int tn = th*4 + q;
        b[q].u = *reinterpret_cast<const uint4*>(W + base_w + tn*16*Wk + ks*32);
      }
      #pragma unroll
      for (int q = 0; q < 4; ++q){
        int tn = th*4 + q;
        acc[0][tn] = __builtin_amdgcn_mfma_f32_16x16x32_bf16(a0.s, b[q].s, acc[0][tn], 0, 0, 0);
        acc[1][tn] = __builtin_amdgcn_mfma_f32_16x16x32_bf16(a1.s, b[q].s, acc[1][tn], 0, 0, 0);
      }
    }
  }
}

// row-wise LayerNorm stats over 512 cols of v (canonical layout)
__device__ __forceinline__ void ln_rows(const f32x4 (&v)[2][8],
    float (&mean)[2][4], float (&rstd)[2][4],
    int wm, int wn, int lr, int lg, int tid,
    float2* __restrict__ red1, float2* __restrict__ red2)
{
  float s[2][4], q[2][4];
  #pragma unroll
  for (int ti = 0; ti < 2; ++ti)
    #pragma unroll
    for (int r = 0; r < 4; ++r){
      float ss = 0.f, qq = 0.f;
      #pragma unroll
      for (int tn = 0; tn < 8; ++tn){ float xv = v[ti][tn][r]; ss += xv; qq += xv*xv; }
      s[ti][r] = ss; q[ti][r] = qq;
    }
  #pragma unroll
  for (int m = 1; m < 16; m <<= 1){
    #pragma unroll
    for (int ti = 0; ti < 2; ++ti)
      #pragma unroll
      for (int r = 0; r < 4; ++r){
        s[ti][r] += __shfl_xor(s[ti][r], m, 64);
        q[ti][r] += __shfl_xor(q[ti][r], m, 64);
      }
  }
  #pragma unroll
  for (int ti = 0; ti < 2; ++ti)
    #pragma unroll
    for (int r = 0; r < 4; ++r)
      if (lr == ti*4 + r){
        int mrow = wm*32 + ti*16 + lg*4 + r;
        red1[mrow*4 + wn] = make_float2(s[ti][r], q[ti][r]);
      }
  __syncthreads();
  if (tid < 64){
    float S = 0.f, Q = 0.f;
    #pragma unroll
    for (int w = 0; w < 4; ++w){ float2 p = red1[tid*4 + w]; S += p.x; Q += p.y; }
    float mu = S * (1.0f/HH);
    float va = Q * (1.0f/HH) - mu*mu;
    red2[tid] = make_float2(mu, rsqrtf(va + 1e-5f));
  }
  __syncthreads();
  #pragma unroll
  for (int ti = 0; ti < 2; ++ti)
    #pragma unroll
    for (int r = 0; r < 4; ++r){
      float2 p = red2[wm*32 + ti*16 + lg*4 + r];
      mean[ti][r] = p.x; rstd[ti][r] = p.y;
    }
}

#define ZERO28(A) { _Pragma("unroll") for (int _i=0;_i<2;++_i) _Pragma("unroll") for (int _j=0;_j<8;++_j) A[_i][_j] = (f32x4){0.f,0.f,0.f,0.f}; }

__global__ __launch_bounds__(512) void liquid_main(
    const float* __restrict__ x,
    const float* __restrict__ b_in,
    const float* __restrict__ b_liq, const float* __restrict__ g_liq, const float* __restrict__ be_liq,
    const float* __restrict__ g_att, const float* __restrict__ be_att,
    const float* __restrict__ tau,
    const float* __restrict__ b1, const float* __restrict__ b2,
    const u16* __restrict__ Wliq_b, const u16* __restrict__ Wov_b, const float* __restrict__ bov,
    const u16* __restrict__ Win_b, const u16* __restrict__ W1_b, const u16* __restrict__ W2_b,
    float* __restrict__ out)
{
  extern __shared__ char smem[];
  u16* A0 = (u16*)smem;                       // [64][STRIDE] bf16 : current matmul operand
  u16* H0 = A0 + RROWS*STRIDE;                // [64][STRIDE] bf16 : h after step 0
  float2* red1 = (float2*)(H0 + RROWS*STRIDE);
  float2* red2 = red1 + RROWS*4;

  const int tid = threadIdx.x;
  const int lane = tid & 63;
  const int wid = tid >> 6;
  const int wm = wid >> 2, wn = wid & 3;
  const int lr = lane & 15, lg = lane >> 4;
  const int rb = blockIdx.x;

  f32x4 acc[2][8], liq[2][8], h[2][8];
  u32 xpk[2][8][2];
  float mean[2][4], rstd[2][4];

  // ---- phase 0: stage x tile into A0 (cols 0..255), compute xin = x@W_in^T + b_in ----
  {
    const float4* xg = reinterpret_cast<const float4*>(x + (size_t)rb * RROWS * IN_F);
    #pragma unroll
    for (int j = 0; j < 8; ++j){
      int i4 = tid + j*512;
      float4 v = xg[i4];
      int m = i4 >> 6;
      int c = (i4 & 63) << 2;
      U16x4 pk;
      pk.h[0]=f2bf(v.x); pk.h[1]=f2bf(v.y); pk.h[2]=f2bf(v.z); pk.h[3]=f2bf(v.w);
      *reinterpret_cast<uint2*>(A0 + m*STRIDE + c) = pk.u;
    }
  }
  __syncthreads();
  ZERO28(acc);
  gemm_tile(A0, Win_b, IN_F, IN_F/32, wm, wn, lr, lg, acc);
  #pragma unroll
  for (int tn = 0; tn < 8; ++tn){
    int n = wn*128 + tn*16 + lr;
    float bi = b_in[n];
    #pragma unroll
    for (int ti = 0; ti < 2; ++ti){
      xpk[ti][tn][0] = (u32)f2bf(acc[ti][tn][0]+bi) | ((u32)f2bf(acc[ti][tn][1]+bi) << 16);
      xpk[ti][tn][1] = (u32)f2bf(acc[ti][tn][2]+bi) | ((u32)f2bf(acc[ti][tn][3]+bi) << 16);
    }
  }
  ZERO28(h);

  // ---- recurrent steps ----
  for (int t = 0; t < NSTEPS; ++t){
    __syncthreads();
    // write h -> A0 (bf16)
    #pragma unroll
    for (int ti = 0; ti < 2; ++ti)
      #pragma unroll
      for (int tn = 0; tn < 8; ++tn){
        int n = wn*128 + tn*16 + lr;
        #pragma unroll
        for (int r = 0; r < 4; ++r){
          int m = wm*32 + ti*16 + lg*4 + r;
          A0[m*STRIDE + n] = f2bf(h[ti][tn][r]);
        }
      }
    __syncthreads();

    ZERO28(liq);
    for (int l = 0; l < NL; ++l){
      ZERO28(acc);
      gemm_tile(A0, Wliq_b + (size_t)l*HH*HH, HH, HH/32, wm, wn, lr, lg, acc);
      // pre = acc + b_liq  (the +h is folded into W via +I)
      #pragma unroll
      for (int tn = 0; tn < 8; ++tn){
        int n = wn*128 + tn*16 + lr;
        float bl = b_liq[l*HH + n];
        #pragma unroll
        for (int ti = 0; ti < 2; ++ti)
          #pragma unroll
          for (int r = 0; r < 4; ++r) acc[ti][tn][r] += bl;
      }
      ln_rows(acc, mean, rstd, wm, wn, lr, lg, tid, red1, red2);
      #pragma unroll
      for (int tn = 0; tn < 8; ++tn){
        int n = wn*128 + tn*16 + lr;
        float gg = g_liq[l*HH + n], bb = be_liq[l*HH + n];
        #pragma unroll
        for (int ti = 0; ti < 2; ++ti)
          #pragma unroll
          for (int r = 0; r < 4; ++r)
            liq[ti][tn][r] += (acc[ti][tn][r] - mean[ti][r]) * rstd[ti][r] * gg + bb;
      }
    }

    // attention (folded): att = liq @ W_ov^T + b_ov
    #pragma unroll
    for (int ti = 0; ti < 2; ++ti)
      #pragma unroll
      for (int tn = 0; tn < 8; ++tn){
        int n = wn*128 + tn*16 + lr;
        #pragma unroll
        for (int r = 0; r < 4; ++r){
          int m = wm*32 + ti*16 + lg*4 + r;
          A0[m*STRIDE + n] = f2bf(liq[ti][tn][r]);
        }
      }
    __syncthreads();
    ZERO28(acc);
    gemm_tile(A0, Wov_b, HH, HH/32, wm, wn, lr, lg, acc);
    #pragma unroll
    for (int tn = 0; tn < 8; ++tn){
      int n = wn*128 + tn*16 + lr;
      float bo_ = bov[n];
      #pragma unroll
      for (int ti = 0; ti < 2; ++ti)
        #pragma unroll
        for (int r = 0; r < 4; ++r)
          acc[ti][tn][r] += bo_ + liq[ti][tn][r];   // att + liq
    }
    ln_rows(acc, mean, rstd, wm, wn, lr, lg, tid, red1, red2);
    // h update: h += (tanh(ln*g+b + xin) - h) / (tau+eps)
    #pragma unroll
    for (int tn = 0; tn < 8; ++tn){
      int n = wn*128 + tn*16 + lr;
      float ga = g_att[n], ba = be_att[n];
      float it = 1.0f / (tau[n] + 1e-6f);
      #pragma unroll
      for (int ti = 0; ti < 2; ++ti)
        #pragma unroll
        for (int r = 0; r < 4; ++r){
          float l2 = (acc[ti][tn][r] - mean[ti][r]) * rstd[ti][r] * ga + ba;
          float xi = bf2f((u16)(xpk[ti][tn][r >> 1] >> ((r & 1) * 16)));
          float th = tanhf(l2 + xi);
          h[ti][tn][r] += (th - h[ti][tn][r]) * it;
        }
    }
    if (t == 0){
      #pragma unroll
      for (int ti = 0; ti < 2; ++ti)
        #pragma unroll
        for (int tn = 0; tn < 8; ++tn){
          int n = wn*128 + tn*16 + lr;
          #pragma unroll
          for (int r = 0; r < 4; ++r){
            int m = wm*32 + ti*16 + lg*4 + r;
            H0[m*STRIDE + n] = f2bf(h[ti][tn][r]);
          }
        }
    }
  }

  // ---- output head: a1 = relu([h, h0] @ W1^T + b1); out = a1 @ W2^T + b2 ----
  __syncthreads();
  #pragma unroll
  for (int ti = 0; ti < 2; ++ti)
    #pragma unroll
    for (int tn = 0; tn < 8; ++tn){
      int n = wn*128 + tn*16 + lr;
      #pragma unroll
      for (int r = 0; r < 4; ++r){
        int m = wm*32 + ti*16 + lg*4 + r;
        A0[m*STRIDE + n] = f2bf(h[ti][tn][r]);
      }
    }
  __syncthreads();
  ZERO28(acc);
  gemm_tile(A0, W1_b,      2*HH, HH/32, wm, wn, lr, lg, acc);  // h part (k 0..511)
  gemm_tile(H0, W1_b + HH, 2*HH, HH/32, wm, wn, lr, lg, acc);  // h0 part (k 512..1023)
  #pragma unroll
  for (int tn = 0; tn < 8; ++tn){
    int n = wn*128 + tn*16 + lr;
    float bb = b1[n];
    #pragma unroll
    for (int ti = 0; ti < 2; ++ti)
      #pragma unroll
      for (int r = 0; r < 4; ++r)
        acc[ti][tn][r] = fmaxf(acc[ti][tn][r] + bb, 0.f);
  }
  __syncthreads();
  #pragma unroll
  for (int ti = 0; ti < 2; ++ti)
    #pragma unroll
    for (int tn = 0; tn < 8; ++tn){
      int n = wn*128 + tn*16 + lr;
      #pragma unroll
      for (int r = 0; r < 4; ++r){
        int m = wm*32 + ti*16 + lg*4 + r;
        A0[m*STRIDE + n] = f2bf(acc[ti][tn][r]);
      }
    }
  __syncthreads();

  // final [64,512] @ W2^T -> [64,128]; remap 8 waves to 4x2
  {
    const int wm2 = wid >> 1, wn2 = wid & 1;
    f32x4 a2[4];
    #pragma unroll
    for (int qn = 0; qn < 4; ++qn) a2[qn] = (f32x4){0.f,0.f,0.f,0.f};
    const int base_a2 = (wm2*16 + lr)*STRIDE + lg*8;
    const int base_w2 = (wn2*64 + lr)*HH + lg*8;
    #pragma unroll 2
    for (int ks = 0; ks < HH/32; ++ks){
      U16x8 aa; aa.u = *reinterpret_cast<const uint4*>(A0 + base_a2 + ks*32);
      #pragma unroll
      for (int qn = 0; qn < 4; ++qn){
        U16x8 bb; bb.u = *reinterpret_cast<const uint4*>(W2_b + base_w2 + qn*16*HH + ks*32);
        a2[qn] = __builtin_amdgcn_mfma_f32_16x16x32_bf16(aa.s, bb.s, a2[qn], 0, 0, 0);
      }
    }
    #pragma unroll
    for (int qn = 0; qn < 4; ++qn){
      int n = wn2*64 + qn*16 + lr;
      float bb = b2[n];
      #pragma unroll
      for (int r = 0; r < 4; ++r){
        int m = wm2*16 + lg*4 + r;
        out[(size_t)(rb*RROWS + m)*OUT_F + n] = a2[qn][r] + bb;
      }
    }
  }
}

// ---------------- launch ----------------

extern "C" void kernel_launch(void* const* d_in, const int* in_sizes, int n_in,
                              void* d_out, int out_size, void* d_ws, size_t ws_size,
                              hipStream_t stream)
{
  (void)in_sizes; (void)n_in; (void)out_size; (void)ws_size;
  const float* x      = (const float*)d_in[0];
  const float* W_in   = (const float*)d_in[1];
  const float* b_in   = (const float*)d_in[2];
  const float* W_liq  = (const float*)d_in[3];
  const float* b_liq  = (const float*)d_in[4];
  const float* g_liq  = (const float*)d_in[5];
  const float* be_liq = (const float*)d_in[6];
  const float* W_v    = (const float*)d_in[7];
  const float* b_v    = (const float*)d_in[8];
  const float* W_o    = (const float*)d_in[9];
  const float* b_o    = (const float*)d_in[10];
  const float* g_att  = (const float*)d_in[11];
  const float* be_att = (const float*)d_in[12];
  const float* tau    = (const float*)d_in[13];
  const float* W1     = (const float*)d_in[14];
  const float* b1     = (const float*)d_in[15];
  const float* W2     = (const float*)d_in[16];
  const float* b2     = (const float*)d_in[17];
  float* out = (float*)d_out;

  u16* ws = (u16*)d_ws;
  u16* wsliq = ws;                         // 3*512*512      = 786432
  u16* wsov  = ws + 786432;                // 512*512        = 262144
  u16* wswin = ws + 1048576;               // 512*256        = 131072
  u16* wsw1  = ws + 1179648;               // 512*1024       = 524288
  u16* wsw2  = ws + 1703936;               // 128*512        = 65536
  float* wsbov = (float*)(ws + 1769472);   // 512 floats

  prep_convert<<<1024, 256, 0, stream>>>(W_liq, W_in, W1, W2, wsliq, wswin, wsw1, wsw2);
  prep_ov<<<512, 256, 0, stream>>>(W_v, W_o, b_v, b_o, wsov, wsbov);

  const int SMEM = RROWS*STRIDE*2*2 + RROWS*4*(int)sizeof(float2) + RROWS*(int)sizeof(float2);
  hipFuncSetAttribute((const void*)liquid_main, hipFuncAttributeMaxDynamicSharedMemorySize, SMEM);
  liquid_main<<<32768/RROWS, 512, SMEM, stream>>>(
      x, b_in, b_liq, g_liq, be_liq, g_att, be_att, tau, b1, b2,
      wsliq, wsov, wsbov, wswin, wsw1, wsw2, out);
}

// Round 2
// 610.703 us; speedup vs baseline: 2.1341x; 2.1341x over previous
//
#include <hip/hip_runtime.h>
#include <hip/hip_bf16.h>

#define HH 512
#define IN_F 256
#define OUT_F 128
#define NSTEPS 3
#define NL 3
#define RROWS 64
#define STRIDE 520   // bf16 elements; 1040B pitch

typedef __attribute__((ext_vector_type(8))) short short8;
typedef __attribute__((ext_vector_type(4))) float f32x4;
typedef unsigned short u16;
typedef unsigned int u32;

union U16x8 { uint4 u; short8 s; u16 h[8]; };
union U16x4 { uint2 u; u16 h[4]; };

static __device__ __forceinline__ float bf2f(u16 v){
  return __uint_as_float(((u32)v) << 16);
}
static __device__ __forceinline__ u16 f2bf(float f){   // RNE bf16
  u32 x = __float_as_uint(f);
  x += 0x7fffu + ((x >> 16) & 1u);
  return (u16)(x >> 16);
}
static __device__ __forceinline__ float fast_tanh(float x){
  float e = __expf(2.0f * x);
  return 1.0f - 2.0f / (e + 1.0f);
}

// ---------------- prep kernels ----------------

__global__ void prep_convert(const float* __restrict__ Wliq, const float* __restrict__ Win,
                             const float* __restrict__ W1, const float* __restrict__ W2,
                             u16* __restrict__ oliq, u16* __restrict__ owin,
                             u16* __restrict__ ow1, u16* __restrict__ ow2)
{
  int tid = blockIdx.x * blockDim.x + threadIdx.x;
  int nt  = gridDim.x * blockDim.x;
  for (int i = tid; i < NL*HH*HH; i += nt){
    int rem = i % (HH*HH);
    int r = rem / HH, c = rem % HH;
    oliq[i] = f2bf(Wliq[i] + ((r == c) ? 1.0f : 0.0f));   // fold +I: pre = h@(W+I)^T + b
  }
  for (int i = tid; i < HH*IN_F;  i += nt) owin[i] = f2bf(Win[i]);
  for (int i = tid; i < HH*2*HH;  i += nt) ow1[i]  = f2bf(W1[i]);
  for (int i = tid; i < OUT_F*HH; i += nt) ow2[i]  = f2bf(W2[i]);
}

// W_ov = W_o @ W_v ; b_ov = W_o @ b_v + b_o  (single-token attention fold)
__global__ void prep_ov(const float* __restrict__ Wv, const float* __restrict__ Wo,
                        const float* __restrict__ bv, const float* __restrict__ bo,
                        u16* __restrict__ oov, float* __restrict__ obov)
{
  __shared__ float srow[HH];
  __shared__ float rbuf[256];
  const int i = blockIdx.x;
  const int t = threadIdx.x;
  srow[t]       = Wo[i*HH + t];
  srow[t + 256] = Wo[i*HH + t + 256];
  __syncthreads();
  #pragma unroll
  for (int half = 0; half < 2; ++half){
    int j = t + half*256;
    float a0 = 0.f, a1 = 0.f;
    for (int k = 0; k < HH; k += 2){
      a0 += srow[k]   * Wv[(k)*HH + j];
      a1 += srow[k+1] * Wv[(k+1)*HH + j];
    }
    oov[i*HH + j] = f2bf(a0 + a1);
  }
  float p = 0.f;
  for (int k = t; k < HH; k += 256) p += srow[k] * bv[k];
  rbuf[t] = p; __syncthreads();
  for (int s = 128; s > 0; s >>= 1){ if (t < s) rbuf[t] += rbuf[t + s]; __syncthreads(); }
  if (t == 0) obov[i] = rbuf[0] + bo[i];
}

// Step-0 collapse: h=0 -> pre_l = b_liq[l] (row-const) -> LN = beta_liq[l] exactly.
// c1 = sum_l beta_liq[l]; v = c1@Wov^T + bov + c1 (row-const); z = LN(v)*g_att+be_att.
// Then h1 = tanh(z + xin) / (tau+eps), purely elementwise.
__global__ void prep_z(const float* __restrict__ be_liq, const float* __restrict__ g_att,
                       const float* __restrict__ be_att, const u16* __restrict__ Wov,
                       const float* __restrict__ bov, float* __restrict__ z_out)
{
  __shared__ float c1s[HH];
  __shared__ float2 rr[HH];
  const int n = threadIdx.x;
  const float c1 = be_liq[n] + be_liq[HH + n] + be_liq[2*HH + n];
  c1s[n] = c1;
  __syncthreads();
  float a = 0.f;
  for (int k = 0; k < HH; ++k) a += c1s[k] * bf2f(Wov[(size_t)n*HH + k]);
  const float v = a + bov[n] + c1;
  rr[n] = make_float2(v, v*v);
  __syncthreads();
  for (int s = 256; s > 0; s >>= 1){
    if (n < s){ rr[n].x += rr[n+s].x; rr[n].y += rr[n+s].y; }
    __syncthreads();
  }
  const float mu = rr[0].x * (1.f/HH);
  const float va = rr[0].y * (1.f/HH) - mu*mu;
  z_out[n] = (v - mu) * rsqrtf(va + 1e-5f) * g_att[n] + be_att[n];
}

// ---------------- main fused kernel ----------------
// 8 waves, wave tile 64 rows x 64 cols (wave grid 1x8 -> no B duplication).

#define ZERO44(A) { _Pragma("unroll") for (int _i=0;_i<4;++_i) _Pragma("unroll") for (int _j=0;_j<4;++_j) A[_i][_j] = (f32x4){0.f,0.f,0.f,0.f}; }

__device__ __forceinline__ void gemm64(const u16* ldsA, const u16* __restrict__ W,
    const int Wk, const int kSteps, const int wid, const int lr, const int lg,
    f32x4 (&acc)[4][4])
{
  const u16* pw = W + (size_t)(wid*64 + lr)*Wk + lg*8;
  const u16* pa = ldsA + lr*STRIDE + lg*8;
  #pragma unroll 2
  for (int ks = 0; ks < kSteps; ++ks){
    U16x8 b[4], a[4];
    #pragma unroll
    for (int tn = 0; tn < 4; ++tn)
      b[tn].u = *reinterpret_cast<const uint4*>(pw + (size_t)tn*16*Wk + ks*32);
    #pragma unroll
    for (int ti = 0; ti < 4; ++ti)
      a[ti].u = *reinterpret_cast<const uint4*>(pa + ti*16*STRIDE + ks*32);
    #pragma unroll
    for (int ti = 0; ti < 4; ++ti)
      #pragma unroll
      for (int tn = 0; tn < 4; ++tn)
        acc[ti][tn] = __builtin_amdgcn_mfma_f32_16x16x32_bf16(a[ti].s, b[tn].s, acc[ti][tn], 0, 0, 0);
  }
}

// per-row LN stats over 512 cols; results land in red2[row] = (mean, rstd)
__device__ __forceinline__ void ln_rows64(const f32x4 (&v)[4][4],
    const int wid, const int lr, const int lg, const int tid,
    float2* __restrict__ red1, float2* __restrict__ red2)
{
  float s[4][4], q[4][4];
  #pragma unroll
  for (int ti = 0; ti < 4; ++ti)
    #pragma unroll
    for (int r = 0; r < 4; ++r){
      float ss = 0.f, qq = 0.f;
      #pragma unroll
      for (int tn = 0; tn < 4; ++tn){ float xv = v[ti][tn][r]; ss += xv; qq += xv*xv; }
      s[ti][r] = ss; q[ti][r] = qq;
    }
  #pragma unroll
  for (int m = 1; m < 16; m <<= 1)
    #pragma unroll
    for (int ti = 0; ti < 4; ++ti)
      #pragma unroll
      for (int r = 0; r < 4; ++r){
        s[ti][r] += __shfl_xor(s[ti][r], m, 64);
        q[ti][r] += __shfl_xor(q[ti][r], m, 64);
      }
  #pragma unroll
  for (int ti = 0; ti < 4; ++ti)
    #pragma unroll
    for (int r = 0; r < 4; ++r)
      if (lr == ti*4 + r)
        red1[(ti*16 + lg*4 + r)*8 + wid] = make_float2(s[ti][r], q[ti][r]);
  __syncthreads();
  if (tid < 64){
    float S = 0.f, Q = 0.f;
    #pragma unroll
    for (int w = 0; w < 8; ++w){ float2 p = red1[tid*8 + w]; S += p.x; Q += p.y; }
    float mu = S * (1.0f/HH);
    float va = Q * (1.0f/HH) - mu*mu;
    red2[tid] = make_float2(mu, rsqrtf(va + 1e-5f));
  }
  __syncthreads();
}

__global__ __launch_bounds__(512, 2) void liquid_main(
    const float* __restrict__ x, const float* __restrict__ b_in,
    const float* __restrict__ b_liq, const float* __restrict__ g_liq, const float* __restrict__ be_liq,
    const float* __restrict__ g_att, const float* __restrict__ be_att,
    const float* __restrict__ tau,
    const float* __restrict__ b1, const float* __restrict__ b2,
    const u16* __restrict__ Wliq_b, const u16* __restrict__ Wov_b, const float* __restrict__ bov,
    const u16* __restrict__ Win_b, const u16* __restrict__ W1_b, const u16* __restrict__ W2_b,
    const float* __restrict__ zv,
    float* __restrict__ out)
{
  extern __shared__ char smem[];
  u16* A0 = (u16*)smem;                        // h buffer (persists through each step)
  u16* L0 = A0 + RROWS*STRIDE;                 // liq / h0 operand buffer
  float2* red1 = (float2*)(L0 + RROWS*STRIDE); // [64][8]
  float2* red2 = red1 + RROWS*8;               // [64]

  const int tid = threadIdx.x;
  const int lane = tid & 63;
  const int wid = tid >> 6;
  const int lr = lane & 15, lg = lane >> 4;
  const int rb = blockIdx.x;

  f32x4 acc[4][4], liq[4][4];
  u32 xpk[4][4][2];

  // ---- phase 0: stage x (bf16) into A0 cols 0..255 ----
  {
    const float4* xg = reinterpret_cast<const float4*>(x + (size_t)rb * RROWS * IN_F);
    #pragma unroll
    for (int j = 0; j < 8; ++j){
      int i4 = tid + j*512;
      float4 v = xg[i4];
      int m = i4 >> 6, c = (i4 & 63) << 2;
      U16x4 pk;
      pk.h[0]=f2bf(v.x); pk.h[1]=f2bf(v.y); pk.h[2]=f2bf(v.z); pk.h[3]=f2bf(v.w);
      *reinterpret_cast<uint2*>(A0 + m*STRIDE + c) = pk.u;
    }
  }
  __syncthreads();
  ZERO44(acc);
  gemm64(A0, Win_b, IN_F, IN_F/32, wid, lr, lg, acc);
  __syncthreads();   // all x-reads of A0 done before h overwrites it

  // xin = x@Win^T + b_in (keep packed bf16); h1 = tanh(z + xin)*it -> A0
  #pragma unroll
  for (int tn = 0; tn < 4; ++tn){
    const int n = wid*64 + tn*16 + lr;
    const float bi = b_in[n];
    const float zn = zv[n];
    const float it = 1.0f/(tau[n] + 1e-6f);
    #pragma unroll
    for (int ti = 0; ti < 4; ++ti){
      float xin[4];
      #pragma unroll
      for (int r = 0; r < 4; ++r) xin[r] = acc[ti][tn][r] + bi;
      xpk[ti][tn][0] = (u32)f2bf(xin[0]) | ((u32)f2bf(xin[1]) << 16);
      xpk[ti][tn][1] = (u32)f2bf(xin[2]) | ((u32)f2bf(xin[3]) << 16);
      #pragma unroll
      for (int r = 0; r < 4; ++r){
        const int m = ti*16 + lg*4 + r;
        A0[m*STRIDE + n] = f2bf(fast_tanh(zn + xin[r]) * it);
      }
    }
  }

  // ---- steps 1..2 (step 0 was collapsed into z) ----
  for (int t = 0; t < NSTEPS-1; ++t){
    __syncthreads();   // h writes visible to all
    ZERO44(liq);
    for (int l = 0; l < NL; ++l){
      ZERO44(acc);
      gemm64(A0, Wliq_b + (size_t)l*HH*HH, HH, HH/32, wid, lr, lg, acc);
      float gl[4], bl[4], bb[4];
      #pragma unroll
      for (int tn = 0; tn < 4; ++tn){
        const int n = wid*64 + tn*16 + lr;
        bb[tn] = b_liq[l*HH + n]; gl[tn] = g_liq[l*HH + n]; bl[tn] = be_liq[l*HH + n];
      }
      #pragma unroll
      for (int tn = 0; tn < 4; ++tn)
        #pragma unroll
        for (int ti = 0; ti < 4; ++ti)
          #pragma unroll
          for (int r = 0; r < 4; ++r) acc[ti][tn][r] += bb[tn];
      ln_rows64(acc, wid, lr, lg, tid, red1, red2);
      #pragma unroll
      for (int ti = 0; ti < 4; ++ti)
        #pragma unroll
        for (int r = 0; r < 4; ++r){
          const float2 st = red2[ti*16 + lg*4 + r];
          #pragma unroll
          for (int tn = 0; tn < 4; ++tn)
            liq[ti][tn][r] += (acc[ti][tn][r] - st.x) * st.y * gl[tn] + bl[tn];
        }
    }

    // liq -> L0 for the folded-attention GEMM (A0 keeps h!)
    #pragma unroll
    for (int ti = 0; ti < 4; ++ti)
      #pragma unroll
      for (int tn = 0; tn < 4; ++tn){
        const int n = wid*64 + tn*16 + lr;
        #pragma unroll
        for (int r = 0; r < 4; ++r)
          L0[(ti*16 + lg*4 + r)*STRIDE + n] = f2bf(liq[ti][tn][r]);
      }
    __syncthreads();
    ZERO44(acc);
    gemm64(L0, Wov_b, HH, HH/32, wid, lr, lg, acc);
    #pragma unroll
    for (int tn = 0; tn < 4; ++tn){
      const int n = wid*64 + tn*16 + lr;
      const float bo_ = bov[n];
      #pragma unroll
      for (int ti = 0; ti < 4; ++ti)
        #pragma unroll
        for (int r = 0; r < 4; ++r)
          acc[ti][tn][r] += bo_ + liq[ti][tn][r];   // att + liq
    }
    ln_rows64(acc, wid, lr, lg, tid, red1, red2);
    // h update in place in A0
    #pragma unroll
    for (int tn = 0; tn < 4; ++tn){
      const int n = wid*64 + tn*16 + lr;
      const float ga = g_att[n], ba = be_att[n];
      const float it = 1.0f/(tau[n] + 1e-6f);
      #pragma unroll
      for (int ti = 0; ti < 4; ++ti)
        #pragma unroll
        for (int r = 0; r < 4; ++r){
          const float2 st = red2[ti*16 + lg*4 + r];
          const float l2 = (acc[ti][tn][r] - st.x) * st.y * ga + ba;
          const float xi = bf2f((u16)(xpk[ti][tn][r >> 1] >> ((r & 1) * 16)));
          const int m = ti*16 + lg*4 + r;
          const float ho = bf2f(A0[m*STRIDE + n]);
          A0[m*STRIDE + n] = f2bf(ho + (fast_tanh(l2 + xi) - ho) * it);
        }
    }
  }

  // ---- head: recompute h0 = tanh(z+xin)*it -> L0 (no storage round-trip) ----
  __syncthreads();
  #pragma unroll
  for (int tn = 0; tn < 4; ++tn){
    const int n = wid*64 + tn*16 + lr;
    const float zn = zv[n];
    const float it = 1.0f/(tau[n] + 1e-6f);
    #pragma unroll
    for (int ti = 0; ti < 4; ++ti)
      #pragma unroll
      for (int r = 0; r < 4; ++r){
        const float xi = bf2f((u16)(xpk[ti][tn][r >> 1] >> ((r & 1) * 16)));
        L0[(ti*16 + lg*4 + r)*STRIDE + n] = f2bf(fast_tanh(zn + xi) * it);
      }
  }
  __syncthreads();
  ZERO44(acc);
  gemm64(A0, W1_b,      2*HH, HH/32, wid, lr, lg, acc);  // h part
  gemm64(L0, W1_b + HH, 2*HH, HH/32, wid, lr, lg, acc);  // h0 part
  #pragma unroll
  for (int tn = 0; tn < 4; ++tn){
    const int n = wid*64 + tn*16 + lr;
    const float bb = b1[n];
    #pragma unroll
    for (int ti = 0; ti < 4; ++ti)
      #pragma unroll
      for (int r = 0; r < 4; ++r)
        acc[ti][tn][r] = fmaxf(acc[ti][tn][r] + bb, 0.f);
  }
  __syncthreads();   // A0 reads (W1a gemm) complete before overwrite
  #pragma unroll
  for (int ti = 0; ti < 4; ++ti)
    #pragma unroll
    for (int tn = 0; tn < 4; ++tn){
      const int n = wid*64 + tn*16 + lr;
      #pragma unroll
      for (int r = 0; r < 4; ++r)
        A0[(ti*16 + lg*4 + r)*STRIDE + n] = f2bf(acc[ti][tn][r]);
    }
  __syncthreads();

  // final [64,512] @ W2^T -> [64,128]; each wave: 64 rows x 16 cols
  {
    f32x4 a2[4];
    #pragma unroll
    for (int ti = 0; ti < 4; ++ti) a2[ti] = (f32x4){0.f,0.f,0.f,0.f};
    const u16* pw2 = W2_b + (size_t)(wid*16 + lr)*HH + lg*8;
    const u16* pa2 = A0 + lr*STRIDE + lg*8;
    #pragma unroll 2
    for (int ks = 0; ks < HH/32; ++ks){
      U16x8 bb2; bb2.u = *reinterpret_cast<const uint4*>(pw2 + ks*32);
      #pragma unroll
      for (int ti = 0; ti < 4; ++ti){
        U16x8 aa; aa.u = *reinterpret_cast<const uint4*>(pa2 + ti*16*STRIDE + ks*32);
        a2[ti] = __builtin_amdgcn_mfma_f32_16x16x32_bf16(aa.s, bb2.s, a2[ti], 0, 0, 0);
      }
    }
    const int n = wid*16 + lr;
    const float bb = b2[n];
    #pragma unroll
    for (int ti = 0; ti < 4; ++ti)
      #pragma unroll
      for (int r = 0; r < 4; ++r){
        const int m = ti*16 + lg*4 + r;
        out[(size_t)(rb*RROWS + m)*OUT_F + n] = a2[ti][r] + bb;
      }
  }
}

// ---------------- launch ----------------

extern "C" void kernel_launch(void* const* d_in, const int* in_sizes, int n_in,
                              void* d_out, int out_size, void* d_ws, size_t ws_size,
                              hipStream_t stream)
{
  (void)in_sizes; (void)n_in; (void)out_size; (void)ws_size;
  const float* x      = (const float*)d_in[0];
  const float* W_in   = (const float*)d_in[1];
  const float* b_in   = (const float*)d_in[2];
  const float* W_liq  = (const float*)d_in[3];
  const float* b_liq  = (const float*)d_in[4];
  const float* g_liq  = (const float*)d_in[5];
  const float* be_liq = (const float*)d_in[6];
  const float* W_v    = (const float*)d_in[7];
  const float* b_v    = (const float*)d_in[8];
  const float* W_o    = (const float*)d_in[9];
  const float* b_o    = (const float*)d_in[10];
  const float* g_att  = (const float*)d_in[11];
  const float* be_att = (const float*)d_in[12];
  const float* tau    = (const float*)d_in[13];
  const float* W1     = (const float*)d_in[14];
  const float* b1     = (const float*)d_in[15];
  const float* W2     = (const float*)d_in[16];
  const float* b2     = (const float*)d_in[17];
  float* out = (float*)d_out;

  u16* ws = (u16*)d_ws;
  u16* wsliq = ws;                         // 3*512*512
  u16* wsov  = ws + 786432;                // 512*512
  u16* wswin = ws + 1048576;               // 512*256
  u16* wsw1  = ws + 1179648;               // 512*1024
  u16* wsw2  = ws + 1703936;               // 128*512
  float* wsbov = (float*)(ws + 1769472);   // 512 f
  float* wsz   = (float*)(ws + 1770496);   // 512 f

  prep_convert<<<1024, 256, 0, stream>>>(W_liq, W_in, W1, W2, wsliq, wswin, wsw1, wsw2);
  prep_ov<<<512, 256, 0, stream>>>(W_v, W_o, b_v, b_o, wsov, wsbov);
  prep_z<<<1, 512, 0, stream>>>(be_liq, g_att, be_att, wsov, wsbov, wsz);

  const int SMEM = 2*RROWS*STRIDE*2 + RROWS*8*(int)sizeof(float2) + RROWS*(int)sizeof(float2);
  hipFuncSetAttribute((const void*)liquid_main, hipFuncAttributeMaxDynamicSharedMemorySize, SMEM);
  liquid_main<<<32768/RROWS, 512, SMEM, stream>>>(
      x, b_in, b_liq, g_liq, be_liq, g_att, be_att, tau, b1, b2,
      wsliq, wsov, wsbov, wswin, wsw1, wsw2, wsz, out);
}